// Round 11
// baseline (424.202 us; speedup 1.0000x reference)
//
#include <hip/hip_runtime.h>
#include <hip/hip_bf16.h>

#define NN 50000
#define NE 800000
#define FIN 128
#define HC 256
#define NEG_SLOPE 0.2f
#define LOG2E 1.4426950408889634f

#define GEMM_BLOCKS 1564  // ceil(NN/64)*2  (64x128 tiles)
#define NPAD 196          // ceil(NN/256) pad-writer blocks (trailing on gemm1)
#define NB_HIST 782       // ceil(NE/1024), 4 entries/thread
#define NB_W1 128         // FIN*HC/256
#define NB_W2 256         // HC*HC/256
#define ELLS 64           // ELL stride (max degree ~45 + pad4 <= 52 < 64)

typedef short bf16x8 __attribute__((ext_vector_type(8)));
typedef float f32x4 __attribute__((ext_vector_type(4)));

__device__ __forceinline__ unsigned short f2bf(float f) {
  unsigned u = __float_as_uint(f);
  u += 0x7fff + ((u >> 16) & 1);  // RTN-even
  return (unsigned short)(u >> 16);
}
__device__ __forceinline__ float bf2f(unsigned short s) {
  return __uint_as_float((unsigned)s << 16);
}
__device__ __forceinline__ float bflo(unsigned u) { return __uint_as_float(u << 16); }
__device__ __forceinline__ float bfhi(unsigned u) { return __uint_as_float(u & 0xffff0000u); }

// ---------------- fused prep: hist + DIRECT ELL scatter + W transposes + guards ------
// counts zeroed by hipMemsetAsync before this launch. The hist atomicAdd's return
// value IS the edge's ELL slot -> ce[d*ELLS + r] written right here. This deletes
// the rank array and the entire 3328-block 8-scan scatter phase (round 5-10 form).
// Cost: random 8B ce writes (line-amplified ~50MB) — but prep's write BW was idle
// (atomic-latency-bound), whereas the scan-scatter was serial work inside gemm1.
// Self-loop + pad entries need FINAL counts -> written by gemm1's trailing blocks.
// Guard rows (one row BEFORE each gather table; a_s guard = -1e30) make poisoned
// pad entries (s = -1) contribute weight exp2(-1e30) = 0 with zero per-edge masking.
__global__ __launch_bounds__(256) void prep_hist(
    const float* __restrict__ W1, unsigned short* __restrict__ W1th,
    unsigned short* __restrict__ W1tl, const float* __restrict__ W2,
    unsigned short* __restrict__ W2th, unsigned short* __restrict__ W2tl,
    const int* __restrict__ ei, int* __restrict__ counts, int2* __restrict__ ce,
    unsigned* __restrict__ gA, unsigned* __restrict__ gB, float* __restrict__ asg) {
  int b = blockIdx.x, t = threadIdx.x;
  if (b < NB_HIST) {
#pragma unroll
    for (int u = 0; u < 4; ++u) {
      int e = b * 1024 + u * 256 + t;
      if (e < NE) {
        int d = ei[NE + e];
        int r = atomicAdd(&counts[d], 1);
        ce[d * ELLS + r] = make_int2(ei[e], e);
      }
    }
  } else if (b < NB_HIST + NB_W1) {
    int j = (b - NB_HIST) * 256 + t;  // j = n*K+k, output-contiguous, K=128
    int n = j >> 7, k = j & 127;
    float v = W1[k * HC + n];
    unsigned short h = f2bf(v);
    W1th[j] = h;
    W1tl[j] = f2bf(v - bf2f(h));
  } else if (b < NB_HIST + NB_W1 + NB_W2) {
    int j = (b - NB_HIST - NB_W1) * 256 + t;  // K=256
    int n = j >> 8, k = j & 255;
    float v = W2[k * HC + n];
    unsigned short h = f2bf(v);
    W2th[j] = h;
    W2tl[j] = f2bf(v - bf2f(h));
  } else {
    // misc: zero gather-table guard rows (256 shorts = 128 uints each), a_s guard
    if (t < 128) { gA[t] = 0; gB[t] = 0; }
    if (t < 8) asg[t] = -1e30f;
  }
}

// ---------------- MFMA GEMM + fused coef, 64x128 tile (round-5 proven loop) ----------
// Cb(bf16) = A_bf16 @ (Bh+Bl)^T(stored [N][K]); 2-term split.
// BK=32, stride-40 LDS (<=2-way banks, free), uint4 VGPR staging (round-6's
// async/BK=64 variant regressed +6us — keep this form). Layer 1 (Af != nullptr):
// A-staging loads fp32 X and converts f2bf in-register (bit-identical to a prep
// pass). Trailing blocks (L1 launch only) are the tiny ELL PAD-WRITERS: one
// thread per dst reads final counts[d] and writes the self-loop + <=3 poisons.
__global__ __launch_bounds__(256) void gemm_coef(
    const unsigned short* __restrict__ A, const float* __restrict__ Af,
    const unsigned short* __restrict__ Bth, const unsigned short* __restrict__ Btl,
    const float* __restrict__ att_s, const float* __restrict__ att_d,
    unsigned short* __restrict__ Cb, float* __restrict__ a_s,
    float* __restrict__ a_d, int M, int K,
    const int* __restrict__ cnts, int2* __restrict__ ce, int gemmN) {
  __shared__ unsigned short sA[64 * 40];    // stride 40 shorts: <=2-way banks (free)
  __shared__ unsigned short sBh[128 * 40];
  __shared__ unsigned short sBl[128 * 40];
  __shared__ float sCS[64][4];
  __shared__ float sCD[64][4];

  int bid = blockIdx.x, t = threadIdx.x;
  if (bid >= gemmN) {
    int d = (bid - gemmN) * 256 + t;
    if (d < NN) {
      int cnt = cnts[d];
      int pad4 = (cnt + 4) & ~3;  // loop bound in agg
      ce[d * ELLS + cnt] = make_int2(d, -1);  // self-loop
      for (int p = cnt + 1; p < pad4; ++p)
        ce[d * ELLS + p] = make_int2(-1, -1);  // poison pads
    }
    return;
  }

  int w = t >> 6, lane = t & 63;
  int quad = lane >> 4, lrow = lane & 15;
  int m0 = (bid >> 1) * 64, n0 = (bid & 1) * 128;
  int rm = (w & 1) * 32, cn = (w >> 1) * 64;

  f32x4 acc[2][4] = {};

  for (int k0 = 0; k0 < K; k0 += 32) {
    // stage A: 64 rows x 4 chunks = 256 -> 1/thread (fp32-convert path for layer 1)
    {
      int row = t >> 2, q = t & 3;
      int gm = m0 + row;
      if (gm >= M) gm = M - 1;
      if (Af) {
        const float4* xp = (const float4*)(Af + (size_t)gm * K + k0 + q * 8);
        float4 f0 = xp[0], f1 = xp[1];
        uint4 h;
        h.x = (unsigned)f2bf(f0.x) | ((unsigned)f2bf(f0.y) << 16);
        h.y = (unsigned)f2bf(f0.z) | ((unsigned)f2bf(f0.w) << 16);
        h.z = (unsigned)f2bf(f1.x) | ((unsigned)f2bf(f1.y) << 16);
        h.w = (unsigned)f2bf(f1.z) | ((unsigned)f2bf(f1.w) << 16);
        *(uint4*)(sA + row * 40 + q * 8) = h;
      } else {
        *(uint4*)(sA + row * 40 + q * 8) = *(const uint4*)(A + (size_t)gm * K + k0 + q * 8);
      }
    }
    // stage B: 128 rows x 4 chunks = 512 -> 2/thread
#pragma unroll
    for (int i = 0; i < 2; ++i) {
      int idx = t + i * 256;
      int row = idx >> 2, q = idx & 3;
      size_t gbx = (size_t)(n0 + row) * K + k0 + q * 8;
      *(uint4*)(sBh + row * 40 + q * 8) = *(const uint4*)(Bth + gbx);
      *(uint4*)(sBl + row * 40 + q * 8) = *(const uint4*)(Btl + gbx);
    }
    __syncthreads();

    bf16x8 fa[2];
#pragma unroll
    for (int mi = 0; mi < 2; ++mi)
      fa[mi] = *(const bf16x8*)(sA + (rm + mi * 16 + lrow) * 40 + quad * 8);
#pragma unroll
    for (int ni = 0; ni < 4; ++ni) {
      bf16x8 fbh = *(const bf16x8*)(sBh + (cn + ni * 16 + lrow) * 40 + quad * 8);
      bf16x8 fbl = *(const bf16x8*)(sBl + (cn + ni * 16 + lrow) * 40 + quad * 8);
#pragma unroll
      for (int mi = 0; mi < 2; ++mi) {
        acc[mi][ni] = __builtin_amdgcn_mfma_f32_16x16x32_bf16(fa[mi], fbh, acc[mi][ni], 0, 0, 0);
        acc[mi][ni] = __builtin_amdgcn_mfma_f32_16x16x32_bf16(fa[mi], fbl, acc[mi][ni], 0, 0, 0);
      }
    }
    __syncthreads();
  }

  // att values for this lane's 4 columns (hoisted; pre-scaled by log2e for exp2)
  float vs[4], vd[4];
#pragma unroll
  for (int ni = 0; ni < 4; ++ni) {
    int gn = n0 + cn + ni * 16 + lrow;
    vs[ni] = att_s[gn] * LOG2E;
    vd[ni] = att_d[gn] * LOG2E;
  }
  int h4e = cn >> 5;  // local head pair base: 0 (cols 0-63) or 2 (cols 64-127)

  // C/D layout: col = lane&15, row = quad*4 + reg  [m89-verified]
#pragma unroll
  for (int mi = 0; mi < 2; ++mi) {
#pragma unroll
    for (int r = 0; r < 4; ++r) {
      int lr = rm + mi * 16 + quad * 4 + r;  // local row 0..63
      int gm = m0 + lr;
      if (gm < M) {
#pragma unroll
        for (int ni = 0; ni < 4; ++ni) {
          int gn = n0 + cn + ni * 16 + lrow;
          Cb[(size_t)gm * HC + gn] = f2bf(acc[mi][ni][r]);
        }
      }
      float pse = acc[mi][0][r] * vs[0] + acc[mi][1][r] * vs[1];
      float pso = acc[mi][2][r] * vs[2] + acc[mi][3][r] * vs[3];
      float pde = acc[mi][0][r] * vd[0] + acc[mi][1][r] * vd[1];
      float pdo = acc[mi][2][r] * vd[2] + acc[mi][3][r] * vd[3];
#pragma unroll
      for (int off = 1; off <= 8; off <<= 1) {
        pse += __shfl_xor(pse, off);
        pso += __shfl_xor(pso, off);
        pde += __shfl_xor(pde, off);
        pdo += __shfl_xor(pdo, off);
      }
      if (lrow == 0) {
        sCS[lr][h4e] = pse;
        sCS[lr][h4e + 1] = pso;
        sCD[lr][h4e] = pde;
        sCD[lr][h4e + 1] = pdo;
      }
    }
  }
  __syncthreads();
  // contiguous 16B coef writeback (one float4 per row per array)
  if (t < 64) {
    int gm = m0 + t;
    if (gm < M) {
      int o = (n0 >> 5);  // 0 or 4
      *(float4*)(a_s + (size_t)gm * 8 + o) = *(const float4*)&sCS[t][0];
      *(float4*)(a_d + (size_t)gm * 8 + o) = *(const float4*)&sCD[t][0];
    }
  }
}

// ---------------- aggregation: one dst per 64-lane wave, ELL rows, 4-edge unroll -----
// Proven floor kernel: four structural variants (32-lane/uint4, 64-lane/uint2,
// 4-edge, 8-edge) all land at 71-72us / 224MB / ~3.6TB/s — random-512B-row gather
// service limit. One-shot waves, grid NN/4 (round-2's persistent+reg-capped form
// collapsed MLP, 3.7x slower). Pads poisoned (s=-1 -> guard rows, weight 0).
__global__ __launch_bounds__(256) void agg_kernel(
    const unsigned short* __restrict__ htb, const float* __restrict__ a_s,
    const float* __restrict__ a_d, const int* __restrict__ cnts,
    const int2* __restrict__ ce, const float* __restrict__ bias,
    unsigned short* __restrict__ outb,
    const float* __restrict__ Wn, const float* __restrict__ bn,
    float* __restrict__ outn) {
  int d = blockIdx.x * 4 + (threadIdx.x >> 6);
  if (d >= NN) return;
  int l = threadIdx.x & 63;
  int hh = l >> 3;
  const uint2* ht2 = (const uint2*)htb;
  float adh = a_d[d * 8 + hh];
  int r0 = d * ELLS;
  int r1 = r0 + ((cnts[d] + 4) & ~3);  // +1 self-loop, padded to x4
  float denom = 0.f;
  float4 acc = {0.f, 0.f, 0.f, 0.f};
  for (int r = r0; r < r1; r += 4) {
    const int4* cp = (const int4*)(ce + r);  // 16B-aligned (r % 4 == 0)
    int4 c01 = cp[0], c23 = cp[1];
    int s[4] = {c01.x, c01.z, c23.x, c23.z};
    float as_[4];
    uint2 q[4];
#pragma unroll
    for (int j = 0; j < 4; ++j) {
      as_[j] = a_s[s[j] * 8 + hh];
      q[j] = ht2[s[j] * 64 + l];
    }
#pragma unroll
    for (int j = 0; j < 4; ++j) {
      float e = as_[j] + adh;
      e = fmaxf(e, NEG_SLOPE * e);
      float w = exp2f(e);
      denom += w;
      acc.x += w * bflo(q[j].x);
      acc.y += w * bfhi(q[j].x);
      acc.z += w * bflo(q[j].y);
      acc.w += w * bfhi(q[j].y);
    }
  }
  float dv = 1.f / denom;  // denom >= self-loop term > 0
  float4 bi = *(const float4*)(bias + l * 4);
  float4 o;
  o.x = fmaxf(fmaf(acc.x, dv, bi.x), 0.f);
  o.y = fmaxf(fmaf(acc.y, dv, bi.y), 0.f);
  o.z = fmaxf(fmaf(acc.z, dv, bi.z), 0.f);
  o.w = fmaxf(fmaf(acc.w, dv, bi.w), 0.f);
  uint2 pb;
  pb.x = (unsigned)f2bf(o.x) | ((unsigned)f2bf(o.y) << 16);
  pb.y = (unsigned)f2bf(o.z) | ((unsigned)f2bf(o.w) << 16);
  ((uint2*)outb)[d * 64 + l] = pb;
  if (outn) {
    float4 wv = *(const float4*)(Wn + l * 4);
    float p = o.x * wv.x + o.y * wv.y + o.z * wv.z + o.w * wv.w;
#pragma unroll
    for (int off = 1; off <= 32; off <<= 1) p += __shfl_xor(p, off);
    if (l == 0) outn[d] = p + bn[0];
  }
}

// ---------------- edge predictions: 16-lane group per edge, 2-edge unroll ------------
// ELL row, bound = cnt exactly (self-loop id=-1 and poisons excluded from the loop).
__global__ __launch_bounds__(256) void edge_pred_kernel(
    const unsigned short* __restrict__ h2b, const int* __restrict__ cnts,
    const int2* __restrict__ ce, const float* __restrict__ We,
    const float* __restrict__ be, float* __restrict__ out) {
  int d = blockIdx.x * 4 + (threadIdx.x >> 6);
  if (d >= NN) return;
  int lane = threadIdx.x & 63;
  int g = lane >> 4, l = lane & 15;
  float b = be[0];
  const uint4* h24 = (const uint4*)h2b;

  uint4 qd0 = h24[d * 32 + l * 2], qd1 = h24[d * 32 + l * 2 + 1];
  float wd[16];
  {
    const float4* wep = (const float4*)(We + l * 16);
    float4 w0 = wep[0], w1 = wep[1], w2 = wep[2], w3 = wep[3];
    wd[0] = bflo(qd0.x) * w0.x;  wd[1] = bfhi(qd0.x) * w0.y;
    wd[2] = bflo(qd0.y) * w0.z;  wd[3] = bfhi(qd0.y) * w0.w;
    wd[4] = bflo(qd0.z) * w1.x;  wd[5] = bfhi(qd0.z) * w1.y;
    wd[6] = bflo(qd0.w) * w1.z;  wd[7] = bfhi(qd0.w) * w1.w;
    wd[8] = bflo(qd1.x) * w2.x;  wd[9] = bfhi(qd1.x) * w2.y;
    wd[10] = bflo(qd1.y) * w2.z; wd[11] = bfhi(qd1.y) * w2.w;
    wd[12] = bflo(qd1.z) * w3.x; wd[13] = bfhi(qd1.z) * w3.y;
    wd[14] = bflo(qd1.w) * w3.z; wd[15] = bfhi(qd1.w) * w3.w;
  }

  int r0 = d * ELLS, r1 = r0 + cnts[d];
  for (int r = r0; r < r1; r += 8) {
    int rr0 = r + g, rr1 = r + 4 + g;
    int s0 = 0, id0 = -1, s1 = 0, id1 = -1;
    if (rr0 < r1) { int2 p = ce[rr0]; s0 = p.x; id0 = p.y; }
    if (rr1 < r1) { int2 p = ce[rr1]; s1 = p.x; id1 = p.y; }
    uint4 a0 = h24[s0 * 32 + l * 2], a1 = h24[s0 * 32 + l * 2 + 1];
    uint4 c0 = h24[s1 * 32 + l * 2], c1 = h24[s1 * 32 + l * 2 + 1];
    float p0 = bflo(a0.x) * wd[0] + bfhi(a0.x) * wd[1] + bflo(a0.y) * wd[2] +
               bfhi(a0.y) * wd[3] + bflo(a0.z) * wd[4] + bfhi(a0.z) * wd[5] +
               bflo(a0.w) * wd[6] + bfhi(a0.w) * wd[7] + bflo(a1.x) * wd[8] +
               bfhi(a1.x) * wd[9] + bflo(a1.y) * wd[10] + bfhi(a1.y) * wd[11] +
               bflo(a1.z) * wd[12] + bfhi(a1.z) * wd[13] + bflo(a1.w) * wd[14] +
               bfhi(a1.w) * wd[15];
    float p1 = bflo(c0.x) * wd[0] + bfhi(c0.x) * wd[1] + bflo(c0.y) * wd[2] +
               bfhi(c0.y) * wd[3] + bflo(c0.z) * wd[4] + bfhi(c0.z) * wd[5] +
               bflo(c0.w) * wd[6] + bfhi(c0.w) * wd[7] + bflo(c1.x) * wd[8] +
               bfhi(c1.x) * wd[9] + bflo(c1.y) * wd[10] + bfhi(c1.y) * wd[11] +
               bflo(c1.z) * wd[12] + bfhi(c1.z) * wd[13] + bflo(c1.w) * wd[14] +
               bfhi(c1.w) * wd[15];
#pragma unroll
    for (int off = 1; off <= 8; off <<= 1) {
      p0 += __shfl_xor(p0, off);
      p1 += __shfl_xor(p1, off);
    }
    if (l == 0) {
      if (id0 >= 0) out[id0] = p0 + b;
      if (id1 >= 0) out[id1] = p1 + b;
    }
  }
}

extern "C" void kernel_launch(void* const* d_in, const int* in_sizes, int n_in,
                              void* d_out, int out_size, void* d_ws, size_t ws_size,
                              hipStream_t stream) {
  const float* x  = (const float*)d_in[0];
  const int* ei   = (const int*)d_in[1];
  const float* W1 = (const float*)d_in[3];
  const float* as1 = (const float*)d_in[4];
  const float* ad1 = (const float*)d_in[5];
  const float* b1 = (const float*)d_in[6];
  const float* W2 = (const float*)d_in[7];
  const float* as2 = (const float*)d_in[8];
  const float* ad2 = (const float*)d_in[9];
  const float* b2 = (const float*)d_in[10];
  const float* We = (const float*)d_in[11];
  const float* be = (const float*)d_in[12];
  const float* Wn = (const float*)d_in[13];
  const float* bn = (const float*)d_in[14];
  float* out = (float*)d_out;

  char* wsp = (char*)d_ws;
  auto alloc = [&](size_t bytes) {
    char* p = wsp;
    wsp += (bytes + 255) & ~(size_t)255;
    return p;
  };
  // gather tables get one guard row (256 shorts) BEFORE the table (s=-1 pads)
  unsigned short* hbAr = (unsigned short*)alloc((size_t)(NN + 1) * HC * 2);
  unsigned short* hbA = hbAr + HC;                                  // gemm out (both layers)
  unsigned short* h1b = (unsigned short*)alloc((size_t)NN * HC * 2); // agg1 out
  unsigned short* hbBr = (unsigned short*)alloc((size_t)(NN + 1) * HC * 2);
  unsigned short* hbB = hbBr + HC;                                  // agg2 out
  float* a_sr = (float*)alloc((size_t)(8 + NN * 8) * 4);
  float* a_s = a_sr + 8;                                            // guard: -1e30
  float* a_d = (float*)alloc((size_t)NN * 8 * 4);
  int2* ce = (int2*)alloc((size_t)NN * ELLS * 8);  // ELL (src, edge-id), 25.6 MB
  int* counts = (int*)alloc((size_t)NN * 4);
  unsigned short* W1th = (unsigned short*)alloc((size_t)FIN * HC * 2);
  unsigned short* W1tl = (unsigned short*)alloc((size_t)FIN * HC * 2);
  unsigned short* W2th = (unsigned short*)alloc((size_t)HC * HC * 2);
  unsigned short* W2tl = (unsigned short*)alloc((size_t)HC * HC * 2);

  // zero hist counters (ce edge entries written by prep; pads by gemm1 trailing)
  hipMemsetAsync(counts, 0, (size_t)NN * 4, stream);

  // fused: histogram + DIRECT ELL scatter + W transposes + guard-row init
  prep_hist<<<NB_HIST + NB_W1 + NB_W2 + 1, 256, 0, stream>>>(
      W1, W1th, W1tl, W2, W2th, W2tl, ei, counts, ce,
      (unsigned*)hbAr, (unsigned*)hbBr, a_sr);

  // layer 1 gemm+coef (fp32-A convert path); trailing blocks write ELL pads
  gemm_coef<<<GEMM_BLOCKS + NPAD, 256, 0, stream>>>(
      (const unsigned short*)nullptr, x, W1th, W1tl, as1, ad1, hbA, a_s, a_d,
      NN, FIN, counts, ce, GEMM_BLOCKS);
  agg_kernel<<<NN / 4, 256, 0, stream>>>(hbA, a_s, a_d, counts, ce, b1, h1b,
                                         (const float*)nullptr, (const float*)nullptr,
                                         (float*)nullptr);

  // layer 2 (node_pred fused into agg epilogue)
  gemm_coef<<<GEMM_BLOCKS, 256, 0, stream>>>(
      h1b, (const float*)nullptr, W2th, W2tl, as2, ad2, hbA, a_s, a_d,
      NN, HC, counts, ce, GEMM_BLOCKS);
  agg_kernel<<<NN / 4, 256, 0, stream>>>(hbA, a_s, a_d, counts, ce, b2, hbB,
                                         Wn, bn, out + NE);

  // edge predictions
  edge_pred_kernel<<<NN / 4, 256, 0, stream>>>(hbB, counts, ce, We, be, out);
}

// Round 12
// 408.653 us; speedup vs baseline: 1.0380x; 1.0380x over previous
//
#include <hip/hip_runtime.h>
#include <hip/hip_bf16.h>

#define NN 50000
#define NE 800000
#define FIN 128
#define HC 256
#define NEG_SLOPE 0.2f
#define LOG2E 1.4426950408889634f

#define GEMM_BLOCKS 1564  // ceil(NN/64)*2  (64x128 tiles)
#define NSCAT 3328        // 416 chunks x 8 XCD copies (chunk = 2048 entries)
#define NB_HIST 782       // ceil(NE/1024), 4 entries/thread
#define NB_W1 128         // FIN*HC/256
#define NB_W2 256         // HC*HC/256
#define ELLS 64           // ELL stride (max degree ~45 + pad4 <= 52 < 64)

typedef short bf16x8 __attribute__((ext_vector_type(8)));
typedef float f32x4 __attribute__((ext_vector_type(4)));

__device__ __forceinline__ unsigned short f2bf(float f) {
  unsigned u = __float_as_uint(f);
  u += 0x7fff + ((u >> 16) & 1);  // RTN-even
  return (unsigned short)(u >> 16);
}
__device__ __forceinline__ float bf2f(unsigned short s) {
  return __uint_as_float((unsigned)s << 16);
}
__device__ __forceinline__ float bflo(unsigned u) { return __uint_as_float(u << 16); }
__device__ __forceinline__ float bfhi(unsigned u) { return __uint_as_float(u & 0xffff0000u); }

// ---------------- fused prep: hist+rank + transpose/split W1,W2 + guards -------------
// counts zeroed by hipMemsetAsync before this launch. The hist atomicAdd's RETURN
// VALUE is the edge's rank within its dst row -> stored to rank[e] (coalesced
// write; deterministic ELL scatter later — no scatter atomics, no scans).
// NOTE (r11 lesson): doing the ce scatter directly HERE regresses (+14us) — the
// dependent atomic->random-write chain made prep a 75us serial stage (VALUBusy
// 0.4%). Keep the scatter as XCD-local scans inside gemm1 where it overlaps.
// Guard rows (one row BEFORE each gather table, a_s guard = -1e30) make poisoned
// pad entries (s = -1) contribute weight exp2(-1e30) = 0 with zero per-edge masking.
__global__ __launch_bounds__(256) void prep_hist(
    const float* __restrict__ W1, unsigned short* __restrict__ W1th,
    unsigned short* __restrict__ W1tl, const float* __restrict__ W2,
    unsigned short* __restrict__ W2th, unsigned short* __restrict__ W2tl,
    const int* __restrict__ ei, int* __restrict__ counts, int* __restrict__ rank,
    unsigned* __restrict__ gA, unsigned* __restrict__ gB, float* __restrict__ asg) {
  int b = blockIdx.x, t = threadIdx.x;
  if (b < NB_HIST) {
#pragma unroll
    for (int u = 0; u < 4; ++u) {
      int e = b * 1024 + u * 256 + t;
      if (e < NE) rank[e] = atomicAdd(&counts[ei[NE + e]], 1);
    }
  } else if (b < NB_HIST + NB_W1) {
    int j = (b - NB_HIST) * 256 + t;  // j = n*K+k, output-contiguous, K=128
    int n = j >> 7, k = j & 127;
    float v = W1[k * HC + n];
    unsigned short h = f2bf(v);
    W1th[j] = h;
    W1tl[j] = f2bf(v - bf2f(h));
  } else if (b < NB_HIST + NB_W1 + NB_W2) {
    int j = (b - NB_HIST - NB_W1) * 256 + t;  // K=256
    int n = j >> 8, k = j & 255;
    float v = W2[k * HC + n];
    unsigned short h = f2bf(v);
    W2th[j] = h;
    W2tl[j] = f2bf(v - bf2f(h));
  } else {
    // misc: zero gather-table guard rows (256 shorts = 128 uints each), a_s guard
    if (t < 128) { gA[t] = 0; gB[t] = 0; }
    if (t < 8) asg[t] = -1e30f;
  }
}

// ---------------- MFMA GEMM + fused coef, 64x128 tile (round-5 proven loop) ----------
// Cb(bf16) = A_bf16 @ (Bh+Bl)^T(stored [N][K]); 2-term split.
// BK=32, stride-40 LDS (<=2-way banks, free), uint4 VGPR staging. Round-6's
// BK=64 + global_load_lds + swizzle variant REGRESSED (+6us: 42KB LDS dropped
// occupancy 5->3 blocks/CU; nothing to pipeline at 2-4 k-steps) — keep this form.
// Round-10's agg+gemm phase fusion also regressed (+11us) — keep kernels split.
// Layer 1 (Af != nullptr): A-staging loads fp32 X directly and converts f2bf
// in-register — same bits as a prep pass, deletes 6250 prep blocks and ~13MB HBM.
// Trailing blocks (L1 launch, bid >= gemmN) run the XCD-LOCAL, ATOMIC-FREE ELL
// scatter: pos = d*ELLS + rank[e]; sid%8 selects a dst range of 6250 so each
// XCD's ce write window (~3.2MB) stays L2-resident. Mapping-independent correctness.
__global__ __launch_bounds__(256) void gemm_coef(
    const unsigned short* __restrict__ A, const float* __restrict__ Af,
    const unsigned short* __restrict__ Bth, const unsigned short* __restrict__ Btl,
    const float* __restrict__ att_s, const float* __restrict__ att_d,
    unsigned short* __restrict__ Cb, float* __restrict__ a_s,
    float* __restrict__ a_d, int M, int K,
    const int* __restrict__ ei, const int* __restrict__ cnts,
    const int* __restrict__ rank, int2* __restrict__ ce, int gemmN) {
  __shared__ unsigned short sA[64 * 40];    // stride 40 shorts: <=2-way banks (free)
  __shared__ unsigned short sBh[128 * 40];
  __shared__ unsigned short sBl[128 * 40];
  __shared__ float sCS[64][4];
  __shared__ float sCD[64][4];

  int bid = blockIdx.x, t = threadIdx.x;
  if (bid >= gemmN) {
    int sid = bid - gemmN;
    int x = sid & 7;        // dst range = presumed XCD of this block
    int c = sid >> 3;       // chunk over the edge list
#pragma unroll
    for (int u = 0; u < 8; ++u) {
      int e = c * 2048 + u * 256 + t;
      if (e < NE + NN) {
        int d = (e < NE) ? ei[NE + e] : e - NE;
        if ((unsigned)d / 6250u == (unsigned)x) {
          if (e < NE) {
            ce[d * ELLS + rank[e]] = make_int2(ei[e], e);
          } else {
            int cnt = cnts[d];
            int pad4 = (cnt + 4) & ~3;  // loop bound in agg
            ce[d * ELLS + cnt] = make_int2(d, -1);  // self-loop
            for (int p = cnt + 1; p < pad4; ++p)
              ce[d * ELLS + p] = make_int2(-1, -1);  // poison pads
          }
        }
      }
    }
    return;
  }

  int w = t >> 6, lane = t & 63;
  int quad = lane >> 4, lrow = lane & 15;
  int m0 = (bid >> 1) * 64, n0 = (bid & 1) * 128;
  int rm = (w & 1) * 32, cn = (w >> 1) * 64;

  f32x4 acc[2][4] = {};

  for (int k0 = 0; k0 < K; k0 += 32) {
    // stage A: 64 rows x 4 chunks = 256 -> 1/thread (fp32-convert path for layer 1)
    {
      int row = t >> 2, q = t & 3;
      int gm = m0 + row;
      if (gm >= M) gm = M - 1;
      if (Af) {
        const float4* xp = (const float4*)(Af + (size_t)gm * K + k0 + q * 8);
        float4 f0 = xp[0], f1 = xp[1];
        uint4 h;
        h.x = (unsigned)f2bf(f0.x) | ((unsigned)f2bf(f0.y) << 16);
        h.y = (unsigned)f2bf(f0.z) | ((unsigned)f2bf(f0.w) << 16);
        h.z = (unsigned)f2bf(f1.x) | ((unsigned)f2bf(f1.y) << 16);
        h.w = (unsigned)f2bf(f1.z) | ((unsigned)f2bf(f1.w) << 16);
        *(uint4*)(sA + row * 40 + q * 8) = h;
      } else {
        *(uint4*)(sA + row * 40 + q * 8) = *(const uint4*)(A + (size_t)gm * K + k0 + q * 8);
      }
    }
    // stage B: 128 rows x 4 chunks = 512 -> 2/thread
#pragma unroll
    for (int i = 0; i < 2; ++i) {
      int idx = t + i * 256;
      int row = idx >> 2, q = idx & 3;
      size_t gbx = (size_t)(n0 + row) * K + k0 + q * 8;
      *(uint4*)(sBh + row * 40 + q * 8) = *(const uint4*)(Bth + gbx);
      *(uint4*)(sBl + row * 40 + q * 8) = *(const uint4*)(Btl + gbx);
    }
    __syncthreads();

    bf16x8 fa[2];
#pragma unroll
    for (int mi = 0; mi < 2; ++mi)
      fa[mi] = *(const bf16x8*)(sA + (rm + mi * 16 + lrow) * 40 + quad * 8);
#pragma unroll
    for (int ni = 0; ni < 4; ++ni) {
      bf16x8 fbh = *(const bf16x8*)(sBh + (cn + ni * 16 + lrow) * 40 + quad * 8);
      bf16x8 fbl = *(const bf16x8*)(sBl + (cn + ni * 16 + lrow) * 40 + quad * 8);
#pragma unroll
      for (int mi = 0; mi < 2; ++mi) {
        acc[mi][ni] = __builtin_amdgcn_mfma_f32_16x16x32_bf16(fa[mi], fbh, acc[mi][ni], 0, 0, 0);
        acc[mi][ni] = __builtin_amdgcn_mfma_f32_16x16x32_bf16(fa[mi], fbl, acc[mi][ni], 0, 0, 0);
      }
    }
    __syncthreads();
  }

  // att values for this lane's 4 columns (hoisted; pre-scaled by log2e for exp2)
  float vs[4], vd[4];
#pragma unroll
  for (int ni = 0; ni < 4; ++ni) {
    int gn = n0 + cn + ni * 16 + lrow;
    vs[ni] = att_s[gn] * LOG2E;
    vd[ni] = att_d[gn] * LOG2E;
  }
  int h4e = cn >> 5;  // local head pair base: 0 (cols 0-63) or 2 (cols 64-127)

  // C/D layout: col = lane&15, row = quad*4 + reg  [m89-verified]
#pragma unroll
  for (int mi = 0; mi < 2; ++mi) {
#pragma unroll
    for (int r = 0; r < 4; ++r) {
      int lr = rm + mi * 16 + quad * 4 + r;  // local row 0..63
      int gm = m0 + lr;
      if (gm < M) {
#pragma unroll
        for (int ni = 0; ni < 4; ++ni) {
          int gn = n0 + cn + ni * 16 + lrow;
          Cb[(size_t)gm * HC + gn] = f2bf(acc[mi][ni][r]);
        }
      }
      float pse = acc[mi][0][r] * vs[0] + acc[mi][1][r] * vs[1];
      float pso = acc[mi][2][r] * vs[2] + acc[mi][3][r] * vs[3];
      float pde = acc[mi][0][r] * vd[0] + acc[mi][1][r] * vd[1];
      float pdo = acc[mi][2][r] * vd[2] + acc[mi][3][r] * vd[3];
#pragma unroll
      for (int off = 1; off <= 8; off <<= 1) {
        pse += __shfl_xor(pse, off);
        pso += __shfl_xor(pso, off);
        pde += __shfl_xor(pde, off);
        pdo += __shfl_xor(pdo, off);
      }
      if (lrow == 0) {
        sCS[lr][h4e] = pse;
        sCS[lr][h4e + 1] = pso;
        sCD[lr][h4e] = pde;
        sCD[lr][h4e + 1] = pdo;
      }
    }
  }
  __syncthreads();
  // contiguous 16B coef writeback (one float4 per row per array)
  if (t < 64) {
    int gm = m0 + t;
    if (gm < M) {
      int o = (n0 >> 5);  // 0 or 4
      *(float4*)(a_s + (size_t)gm * 8 + o) = *(const float4*)&sCS[t][0];
      *(float4*)(a_d + (size_t)gm * 8 + o) = *(const float4*)&sCD[t][0];
    }
  }
}

// ---------------- aggregation: one dst per 64-lane wave, ELL rows, 4-edge unroll -----
// Proven floor kernel: four structural variants (32-lane/uint4, 64-lane/uint2,
// 4-edge, 8-edge) all land at 71-72us / 224MB / ~3.6TB/s. The 25.6MB table is
// L3-resident; FETCH=224MB @3.6TB/s is the L3 random-512B-gather service rate.
// One-shot waves, grid NN/4 (round-2's persistent+reg-capped form collapsed MLP,
// 3.7x slower). Pads poisoned (s=-1 -> guard rows, weight exp2(-1e30)=0).
__global__ __launch_bounds__(256) void agg_kernel(
    const unsigned short* __restrict__ htb, const float* __restrict__ a_s,
    const float* __restrict__ a_d, const int* __restrict__ cnts,
    const int2* __restrict__ ce, const float* __restrict__ bias,
    unsigned short* __restrict__ outb,
    const float* __restrict__ Wn, const float* __restrict__ bn,
    float* __restrict__ outn) {
  int d = blockIdx.x * 4 + (threadIdx.x >> 6);
  if (d >= NN) return;
  int l = threadIdx.x & 63;
  int hh = l >> 3;
  const uint2* ht2 = (const uint2*)htb;
  float adh = a_d[d * 8 + hh];
  int r0 = d * ELLS;
  int r1 = r0 + ((cnts[d] + 4) & ~3);  // +1 self-loop, padded to x4
  float denom = 0.f;
  float4 acc = {0.f, 0.f, 0.f, 0.f};
  for (int r = r0; r < r1; r += 4) {
    const int4* cp = (const int4*)(ce + r);  // 16B-aligned (r % 4 == 0)
    int4 c01 = cp[0], c23 = cp[1];
    int s[4] = {c01.x, c01.z, c23.x, c23.z};
    float as_[4];
    uint2 q[4];
#pragma unroll
    for (int j = 0; j < 4; ++j) {
      as_[j] = a_s[s[j] * 8 + hh];
      q[j] = ht2[s[j] * 64 + l];
    }
#pragma unroll
    for (int j = 0; j < 4; ++j) {
      float e = as_[j] + adh;
      e = fmaxf(e, NEG_SLOPE * e);
      float w = exp2f(e);
      denom += w;
      acc.x += w * bflo(q[j].x);
      acc.y += w * bfhi(q[j].x);
      acc.z += w * bflo(q[j].y);
      acc.w += w * bfhi(q[j].y);
    }
  }
  float dv = 1.f / denom;  // denom >= self-loop term > 0
  float4 bi = *(const float4*)(bias + l * 4);
  float4 o;
  o.x = fmaxf(fmaf(acc.x, dv, bi.x), 0.f);
  o.y = fmaxf(fmaf(acc.y, dv, bi.y), 0.f);
  o.z = fmaxf(fmaf(acc.z, dv, bi.z), 0.f);
  o.w = fmaxf(fmaf(acc.w, dv, bi.w), 0.f);
  uint2 pb;
  pb.x = (unsigned)f2bf(o.x) | ((unsigned)f2bf(o.y) << 16);
  pb.y = (unsigned)f2bf(o.z) | ((unsigned)f2bf(o.w) << 16);
  ((uint2*)outb)[d * 64 + l] = pb;
  if (outn) {
    float4 wv = *(const float4*)(Wn + l * 4);
    float p = o.x * wv.x + o.y * wv.y + o.z * wv.z + o.w * wv.w;
#pragma unroll
    for (int off = 1; off <= 32; off <<= 1) p += __shfl_xor(p, off);
    if (l == 0) outn[d] = p + bn[0];
  }
}

// ---------------- edge predictions: 16-lane group per edge, 2-edge unroll ------------
// Pad entries (s=-1) read the guard row before h2b (id=-1 suppresses the store).
__global__ __launch_bounds__(256) void edge_pred_kernel(
    const unsigned short* __restrict__ h2b, const int* __restrict__ cnts,
    const int2* __restrict__ ce, const float* __restrict__ We,
    const float* __restrict__ be, float* __restrict__ out) {
  int d = blockIdx.x * 4 + (threadIdx.x >> 6);
  if (d >= NN) return;
  int lane = threadIdx.x & 63;
  int g = lane >> 4, l = lane & 15;
  float b = be[0];
  const uint4* h24 = (const uint4*)h2b;

  uint4 qd0 = h24[d * 32 + l * 2], qd1 = h24[d * 32 + l * 2 + 1];
  float wd[16];
  {
    const float4* wep = (const float4*)(We + l * 16);
    float4 w0 = wep[0], w1 = wep[1], w2 = wep[2], w3 = wep[3];
    wd[0] = bflo(qd0.x) * w0.x;  wd[1] = bfhi(qd0.x) * w0.y;
    wd[2] = bflo(qd0.y) * w0.z;  wd[3] = bfhi(qd0.y) * w0.w;
    wd[4] = bflo(qd0.z) * w1.x;  wd[5] = bfhi(qd0.z) * w1.y;
    wd[6] = bflo(qd0.w) * w1.z;  wd[7] = bfhi(qd0.w) * w1.w;
    wd[8] = bflo(qd1.x) * w2.x;  wd[9] = bfhi(qd1.x) * w2.y;
    wd[10] = bflo(qd1.y) * w2.z; wd[11] = bfhi(qd1.y) * w2.w;
    wd[12] = bflo(qd1.z) * w3.x; wd[13] = bfhi(qd1.z) * w3.y;
    wd[14] = bflo(qd1.w) * w3.z; wd[15] = bfhi(qd1.w) * w3.w;
  }

  int r0 = d * ELLS, r1 = r0 + cnts[d];
  for (int r = r0; r < r1; r += 8) {
    int rr0 = r + g, rr1 = r + 4 + g;
    int s0 = 0, id0 = -1, s1 = 0, id1 = -1;
    if (rr0 < r1) { int2 p = ce[rr0]; s0 = p.x; id0 = p.y; }
    if (rr1 < r1) { int2 p = ce[rr1]; s1 = p.x; id1 = p.y; }
    uint4 a0 = h24[s0 * 32 + l * 2], a1 = h24[s0 * 32 + l * 2 + 1];
    uint4 c0 = h24[s1 * 32 + l * 2], c1 = h24[s1 * 32 + l * 2 + 1];
    float p0 = bflo(a0.x) * wd[0] + bfhi(a0.x) * wd[1] + bflo(a0.y) * wd[2] +
               bfhi(a0.y) * wd[3] + bflo(a0.z) * wd[4] + bfhi(a0.z) * wd[5] +
               bflo(a0.w) * wd[6] + bfhi(a0.w) * wd[7] + bflo(a1.x) * wd[8] +
               bfhi(a1.x) * wd[9] + bflo(a1.y) * wd[10] + bfhi(a1.y) * wd[11] +
               bflo(a1.z) * wd[12] + bfhi(a1.z) * wd[13] + bflo(a1.w) * wd[14] +
               bfhi(a1.w) * wd[15];
    float p1 = bflo(c0.x) * wd[0] + bfhi(c0.x) * wd[1] + bflo(c0.y) * wd[2] +
               bfhi(c0.y) * wd[3] + bflo(c0.z) * wd[4] + bfhi(c0.z) * wd[5] +
               bflo(c0.w) * wd[6] + bfhi(c0.w) * wd[7] + bflo(c1.x) * wd[8] +
               bfhi(c1.x) * wd[9] + bflo(c1.y) * wd[10] + bfhi(c1.y) * wd[11] +
               bflo(c1.z) * wd[12] + bfhi(c1.z) * wd[13] + bflo(c1.w) * wd[14] +
               bfhi(c1.w) * wd[15];
#pragma unroll
    for (int off = 1; off <= 8; off <<= 1) {
      p0 += __shfl_xor(p0, off);
      p1 += __shfl_xor(p1, off);
    }
    if (l == 0) {
      if (id0 >= 0) out[id0] = p0 + b;
      if (id1 >= 0) out[id1] = p1 + b;
    }
  }
}

extern "C" void kernel_launch(void* const* d_in, const int* in_sizes, int n_in,
                              void* d_out, int out_size, void* d_ws, size_t ws_size,
                              hipStream_t stream) {
  const float* x  = (const float*)d_in[0];
  const int* ei   = (const int*)d_in[1];
  const float* W1 = (const float*)d_in[3];
  const float* as1 = (const float*)d_in[4];
  const float* ad1 = (const float*)d_in[5];
  const float* b1 = (const float*)d_in[6];
  const float* W2 = (const float*)d_in[7];
  const float* as2 = (const float*)d_in[8];
  const float* ad2 = (const float*)d_in[9];
  const float* b2 = (const float*)d_in[10];
  const float* We = (const float*)d_in[11];
  const float* be = (const float*)d_in[12];
  const float* Wn = (const float*)d_in[13];
  const float* bn = (const float*)d_in[14];
  float* out = (float*)d_out;

  char* wsp = (char*)d_ws;
  auto alloc = [&](size_t bytes) {
    char* p = wsp;
    wsp += (bytes + 255) & ~(size_t)255;
    return p;
  };
  // gather tables get one guard row (256 shorts) BEFORE the table (s=-1 pads)
  unsigned short* hbAr = (unsigned short*)alloc((size_t)(NN + 1) * HC * 2);
  unsigned short* hbA = hbAr + HC;                                  // gemm out (both layers)
  unsigned short* h1b = (unsigned short*)alloc((size_t)NN * HC * 2); // agg1 out
  unsigned short* hbBr = (unsigned short*)alloc((size_t)(NN + 1) * HC * 2);
  unsigned short* hbB = hbBr + HC;                                  // agg2 out
  float* a_sr = (float*)alloc((size_t)(8 + NN * 8) * 4);
  float* a_s = a_sr + 8;                                            // guard: -1e30
  float* a_d = (float*)alloc((size_t)NN * 8 * 4);
  int2* ce = (int2*)alloc((size_t)NN * ELLS * 8);  // ELL (src, edge-id), 25.6 MB
  int* counts = (int*)alloc((size_t)NN * 4);
  int* rank = (int*)alloc((size_t)NE * 4);
  unsigned short* W1th = (unsigned short*)alloc((size_t)FIN * HC * 2);
  unsigned short* W1tl = (unsigned short*)alloc((size_t)FIN * HC * 2);
  unsigned short* W2th = (unsigned short*)alloc((size_t)HC * HC * 2);
  unsigned short* W2tl = (unsigned short*)alloc((size_t)HC * HC * 2);

  // zero hist counters (rank & ce fully written by prep/scatter — no init needed)
  hipMemsetAsync(counts, 0, (size_t)NN * 4, stream);

  // fused: histogram+rank + W transposes + guard-row init (X conversion in gemm1)
  prep_hist<<<NB_HIST + NB_W1 + NB_W2 + 1, 256, 0, stream>>>(
      W1, W1th, W1tl, W2, W2th, W2tl, ei, counts, rank,
      (unsigned*)hbAr, (unsigned*)hbBr, a_sr);

  // layer 1 gemm+coef (fp32-A convert path), ELL scatter in TRAILING blocks
  gemm_coef<<<GEMM_BLOCKS + NSCAT, 256, 0, stream>>>(
      (const unsigned short*)nullptr, x, W1th, W1tl, as1, ad1, hbA, a_s, a_d,
      NN, FIN, ei, counts, rank, ce, GEMM_BLOCKS);
  agg_kernel<<<NN / 4, 256, 0, stream>>>(hbA, a_s, a_d, counts, ce, b1, h1b,
                                         (const float*)nullptr, (const float*)nullptr,
                                         (float*)nullptr);

  // layer 2 (node_pred fused into agg epilogue)
  gemm_coef<<<GEMM_BLOCKS, 256, 0, stream>>>(
      h1b, (const float*)nullptr, W2th, W2tl, as2, ad2, hbA, a_s, a_d,
      NN, HC, (const int*)nullptr, counts, rank, ce, GEMM_BLOCKS);
  agg_kernel<<<NN / 4, 256, 0, stream>>>(hbA, a_s, a_d, counts, ce, b2, hbB,
                                         Wn, bn, out + NE);

  // edge predictions
  edge_pred_kernel<<<NN / 4, 256, 0, stream>>>(hbB, counts, ce, We, be, out);
}